// Round 16
// baseline (456.092 us; speedup 1.0000x reference)
//
#include <hip/hip_runtime.h>
#include <hip/hip_bf16.h>
#include <cstdint>
#include <cstddef>

typedef __attribute__((ext_vector_type(4))) float f32x4;
typedef __attribute__((ext_vector_type(4))) short s16x4;
typedef __attribute__((ext_vector_type(8))) short s16x8;

#define SLQ 2048
#define SLK 2048
#define SNH 32
#define SDH 128

__device__ __forceinline__ short f2bf(float x) {
  unsigned u = __builtin_bit_cast(unsigned, x);
  u += 0x7FFF + ((u >> 16) & 1);   // round-to-nearest-even
  return (short)(u >> 16);
}

__device__ __forceinline__ void gload_lds16(const void* g, const void* l) {
  __builtin_amdgcn_global_load_lds((const __attribute__((address_space(1))) void*)g,
                                   (__attribute__((address_space(3))) void*)l,
                                   16, 0, 0);
}

// DPP 16-lane-row reductions (VALU pipe): row_ror:8/4/2/1
template<int CTRL>
__device__ __forceinline__ float dpp_f32(float x) {
  return __builtin_bit_cast(float, __builtin_amdgcn_update_dpp(
      0, __builtin_bit_cast(int, x), CTRL, 0xF, 0xF, true));
}
__device__ __forceinline__ float rowmax16(float x) {
  x = fmaxf(x, dpp_f32<0x128>(x));
  x = fmaxf(x, dpp_f32<0x124>(x));
  x = fmaxf(x, dpp_f32<0x122>(x));
  x = fmaxf(x, dpp_f32<0x121>(x));
  return x;
}
__device__ __forceinline__ float rowsum16(float x) {
  x += dpp_f32<0x128>(x);
  x += dpp_f32<0x124>(x);
  x += dpp_f32<0x122>(x);
  x += dpp_f32<0x121>(x);
  return x;
}

// f32 -> bf16 elementwise
__global__ void convert_bf16(const float* __restrict__ in, short* __restrict__ out, int n4) {
  int i = blockIdx.x * 256 + threadIdx.x;
  if (i < n4) {
    f32x4 a = ((const f32x4*)in)[i];
    s16x4 b;
    b[0] = f2bf(a[0]); b[1] = f2bf(a[1]); b[2] = f2bf(a[2]); b[3] = f2bf(a[3]);
    ((s16x4*)out)[i] = b;
  }
}

// W [K][N] f32 -> Wt [N][K] bf16. 64x64 tiles.
__global__ void transpose_convert(const float* __restrict__ W, short* __restrict__ Wt,
                                  int K, int N) {
  __shared__ short T[64][68];
  const int tid = threadIdx.x;
  const int k0 = blockIdx.y * 64, n0 = blockIdx.x * 64;
  const int r = tid >> 4;
  const int c4 = (tid & 15) * 4;
#pragma unroll
  for (int i = 0; i < 4; ++i) {
    f32x4 a = *(const f32x4*)(W + (size_t)(k0 + r + i * 16) * N + n0 + c4);
#pragma unroll
    for (int j = 0; j < 4; ++j) T[c4 + j][r + i * 16] = f2bf(a[j]);
  }
  __syncthreads();
  const int rn = tid >> 3;
  const int c8 = (tid & 7) * 8;
#pragma unroll
  for (int i = 0; i < 2; ++i) {
    s16x4 v0 = *(const s16x4*)&T[rn + i * 32][c8];
    s16x4 v1 = *(const s16x4*)&T[rn + i * 32][c8 + 4];
    short* dst = Wt + (size_t)(n0 + rn + i * 32) * K + k0 + c8;
    *(s16x4*)dst = v0;
    *(s16x4*)(dst + 4) = v1;
  }
}

// ---------------------------------------------------------------------------
// gemm_big: C[2048][4096] = A[2048][4096] @ Bt[4096][4096]^T * scale
// BM=128, BN=256, BK=64, 8 waves (2x4), 3-deep LDS pipeline, counted vmcnt.
// XCD column-affinity (r11, -6.5us): XCD x owns n-columns {2x,2x+1}.
// ---------------------------------------------------------------------------
template<int CM>
__global__ __launch_bounds__(512, 1)
void gemm_big(const short* __restrict__ A, const short* __restrict__ Bt,
              void* __restrict__ Cv, float scale) {
  __shared__ short As[3][128 * 64];
  __shared__ short Bs[3][256 * 64];
  const int N = 4096, K = 4096;
  const int tid = threadIdx.x, lane = tid & 63, w = tid >> 6;
  const int l15 = lane & 15, lg = lane >> 4;
  const int wr = w >> 2, wc = w & 3;
  const int b = blockIdx.x;
  const int cp = b & 7, wi = b >> 3;
  const int m0 = (wi >> 1) * 128;
  const int n0 = (cp * 2 + (wi & 1)) * 256;

  f32x4 acc[4][4];
#pragma unroll
  for (int a = 0; a < 4; ++a)
#pragma unroll
    for (int c = 0; c < 4; ++c)
      acc[a][c] = (f32x4){0.f, 0.f, 0.f, 0.f};

#define GSTAGE(T, BUF) do {                                                    \
    _Pragma("unroll") for (int i_ = 0; i_ < 2; ++i_) {                         \
      const int ci = i_ * 512 + tid, r_ = ci >> 3, c_ = ci & 7;                \
      gload_lds16(A + (size_t)(m0 + r_) * K + (T) * 64 + ((c_ ^ (r_ & 7)) * 8),\
                  (const short*)As[BUF] + ci * 8); }                           \
    _Pragma("unroll") for (int i_ = 0; i_ < 4; ++i_) {                         \
      const int ci = i_ * 512 + tid, r_ = ci >> 3, c_ = ci & 7;                \
      gload_lds16(Bt + (size_t)(n0 + r_) * K + (T) * 64 + ((c_ ^ (r_ & 7)) * 8),\
                  (const short*)Bs[BUF] + ci * 8); }                           \
  } while (0)

  const int NT = K >> 6;
  GSTAGE(0, 0); GSTAGE(1, 1); GSTAGE(2, 2);
  int buf = 0;
  for (int t = 0; t < NT; ++t) {
    if (t + 2 < NT)      asm volatile("s_waitcnt vmcnt(12)" ::: "memory");
    else if (t + 1 < NT) asm volatile("s_waitcnt vmcnt(6)" ::: "memory");
    else                 asm volatile("s_waitcnt vmcnt(0)" ::: "memory");
    __builtin_amdgcn_s_barrier();
    const short* Ab = As[buf];
    const short* Bb = Bs[buf];
    s16x8 af[2][4], bfv[2][4];
#pragma unroll
    for (int kk = 0; kk < 2; ++kk) {
#pragma unroll
      for (int mi = 0; mi < 4; ++mi) {
        const int r = wr * 64 + mi * 16 + l15;
        const int c = (kk * 4 + lg) ^ (r & 7);
        af[kk][mi] = *(const s16x8*)(Ab + (r * 8 + c) * 8);
      }
#pragma unroll
      for (int ni = 0; ni < 4; ++ni) {
        const int r = wc * 64 + ni * 16 + l15;
        const int c = (kk * 4 + lg) ^ (r & 7);
        bfv[kk][ni] = *(const s16x8*)(Bb + (r * 8 + c) * 8);
      }
    }
    __builtin_amdgcn_s_setprio(1);
#pragma unroll
    for (int kk = 0; kk < 2; ++kk)
#pragma unroll
      for (int mi = 0; mi < 4; ++mi)
#pragma unroll
        for (int ni = 0; ni < 4; ++ni)
          acc[mi][ni] = __builtin_amdgcn_mfma_f32_16x16x32_bf16(af[kk][mi], bfv[kk][ni], acc[mi][ni], 0, 0, 0);
    __builtin_amdgcn_s_setprio(0);
    __builtin_amdgcn_s_barrier();
    if (t + 3 < NT) GSTAGE(t + 3, buf);
    buf = (buf == 2) ? 0 : buf + 1;
  }
#undef GSTAGE
#pragma unroll
  for (int mi = 0; mi < 4; ++mi) {
#pragma unroll
    for (int ni = 0; ni < 4; ++ni) {
#pragma unroll
      for (int j = 0; j < 4; ++j) {
        const int rg = m0 + wr * 64 + mi * 16 + lg * 4 + j;
        const int cg = n0 + wc * 64 + ni * 16 + l15;
        const float vv = acc[mi][ni][j] * scale;
        if (CM == 0) ((short*)Cv)[(size_t)rg * N + cg] = f2bf(vv);
        else         ((float*)Cv)[(size_t)rg * N + cg] = vv;
      }
    }
  }
}

// ---------------------------------------------------------------------------
// gemm_kv: fused K,V projection. n < 1024 -> kout*inv4 ; else vT transposed.
// ---------------------------------------------------------------------------
__global__ __launch_bounds__(256, 2)
void gemm_kv(const short* __restrict__ A, const short* __restrict__ Bt,
             short* __restrict__ kout, short* __restrict__ vTout, float inv4) {
  __shared__ short As[128][32];
  __shared__ short Bs[128][32];
  const int N = 2048, K = 4096;
  const int tid = threadIdx.x, lane = tid & 63, wid = tid >> 6;
  const int l15 = lane & 15, lg = lane >> 4;
  const int nbx = N >> 7;
  const int nwg = gridDim.x, b = blockIdx.x;
  const int wg = (b & 7) * (nwg >> 3) + (b >> 3);
  const int m0 = (wg / nbx) * 128, n0 = (wg % nbx) * 128;
  const int wm = (wid >> 1) * 64, wn = (wid & 1) * 64;

  f32x4 acc[4][4];
#pragma unroll
  for (int a = 0; a < 4; ++a)
#pragma unroll
    for (int c = 0; c < 4; ++c)
      acc[a][c] = (f32x4){0.f, 0.f, 0.f, 0.f};

  for (int k0 = 0; k0 < K; k0 += 32) {
#pragma unroll
    for (int i = 0; i < 2; ++i) {
      const int c = i * 256 + wid * 64 + lane;
      const int rr = c >> 2, hh = (c & 3) * 8;
      gload_lds16(A  + (size_t)(m0 + rr) * K + k0 + hh,
                  (const short*)As + (size_t)(i * 256 + wid * 64) * 8);
      gload_lds16(Bt + (size_t)(n0 + rr) * K + k0 + hh,
                  (const short*)Bs + (size_t)(i * 256 + wid * 64) * 8);
    }
    __syncthreads();
    s16x8 af[4], bf[4];
#pragma unroll
    for (int mi = 0; mi < 4; ++mi)
      af[mi] = *(const s16x8*)&As[wm + mi * 16 + l15][lg * 8];
#pragma unroll
    for (int ni = 0; ni < 4; ++ni)
      bf[ni] = *(const s16x8*)&Bs[wn + ni * 16 + l15][lg * 8];
#pragma unroll
    for (int mi = 0; mi < 4; ++mi)
#pragma unroll
      for (int ni = 0; ni < 4; ++ni)
        acc[mi][ni] = __builtin_amdgcn_mfma_f32_16x16x32_bf16(af[mi], bf[ni], acc[mi][ni], 0, 0, 0);
    __syncthreads();
  }
  if (n0 < 1024) {
#pragma unroll
    for (int mi = 0; mi < 4; ++mi)
#pragma unroll
      for (int ni = 0; ni < 4; ++ni)
#pragma unroll
        for (int j = 0; j < 4; ++j) {
          const int rg = m0 + wm + mi * 16 + lg * 4 + j;
          const int cg = n0 + wn + ni * 16 + l15;
          kout[(size_t)rg * 1024 + cg] = f2bf(acc[mi][ni][j] * inv4);
        }
  } else {
#pragma unroll
    for (int mi = 0; mi < 4; ++mi)
#pragma unroll
      for (int ni = 0; ni < 4; ++ni) {
        s16x4 wv;
#pragma unroll
        for (int j = 0; j < 4; ++j) wv[j] = f2bf(acc[mi][ni][j]);
        const int rg0 = m0 + wm + mi * 16 + lg * 4;
        const int cg = n0 + wn + ni * 16 + l15 - 1024;
        *(s16x4*)(vTout + (size_t)cg * 2048 + rg0) = wv;
      }
  }
}

// ---------------------------------------------------------------------------
// Flash attention v11: HEAD-PAIRING. Each block = 2 heads (same kvh group)
// x one 64-row q-tile. Per barrier pair: 2x QK + 2x softmax + 2x PV share
// ONE K/V staging + wait set -> per-unit-work overhead halves; K/V stage
// traffic halves (512 blocks). v4 phase structure otherwise.
// LDS: Ks 16K + Vs dbuf 32K + Ps 9K = 57 KB -> 2 blocks/CU.
// vmcnt ledger: outstanding at iter top = V4+K4+bias32 -> vmcnt(32) drains
// exactly V,K; bias register loads are compiler-waited before use.
// ---------------------------------------------------------------------------
__global__ __launch_bounds__(256, 2)
void attn_kernel(const short* __restrict__ q, const short* __restrict__ k,
                 const short* __restrict__ vT, const float* __restrict__ bias,
                 short* __restrict__ o) {
  __shared__ __align__(16) short Ks[64 * 128];
  __shared__ __align__(16) short Vs[2][128 * 64];
  __shared__ __align__(16) short Ps[4][16][72];
  const int tid = threadIdx.x, lane = tid & 63, w = tid >> 6;
  const int l15 = lane & 15, lg = lane >> 4;
  const int b = blockIdx.x;                 // 0..511
  const int hp = b & 15;                    // head pair
  const int qt = 31 - (b >> 4);             // long blocks first
  const int kvh = hp >> 1;
  const int hA = kvh * 4 + (hp & 1) * 2;
  const int hB = hA + 1;
  const int nt = qt + 1;

#define STAGE_K(IT) do { const int kv0_ = (IT) * 64;                          \
    _Pragma("unroll") for (int i_ = 0; i_ < 4; ++i_) {                        \
      const int ci = i_ * 256 + tid, r_ = ci >> 4, c_ = ci & 15;              \
      gload_lds16(k + (size_t)(kv0_ + r_) * 1024 + kvh * 128 + ((c_ ^ (r_ & 7)) * 8), \
                  (const short*)Ks + ci * 8); } } while (0)

#define STAGE_V(IT, P) do { const int kv0_ = (IT) * 64;                       \
    _Pragma("unroll") for (int i_ = 0; i_ < 4; ++i_) {                        \
      const int ci = i_ * 256 + tid, r_ = ci >> 3, c_ = ci & 7;               \
      gload_lds16(vT + (size_t)(kvh * 128 + r_) * 2048 + kv0_ + ((c_ ^ (r_ & 7)) * 8), \
                  (const short*)Vs[P] + ci * 8); } } while (0)

  const int qrow0 = qt * 64 + w * 16 + lg * 4;

  float bbA[4][4], bbB[4][4];
#define LOAD_BIAS(IT, BB, H) do { const float* bp_ = bias + ((size_t)(H) * SLQ + qrow0) * SLK + (IT) * 64 + l15; \
    _Pragma("unroll") for (int ni_ = 0; ni_ < 4; ++ni_)                       \
      _Pragma("unroll") for (int j_ = 0; j_ < 4; ++j_)                        \
        BB[ni_][j_] = bp_[(size_t)j_ * SLK + ni_ * 16]; } while (0)

  // hoist Q fragments for both heads
  s16x8 qfA[4], qfB[4];
  {
    const short* qp = q + (size_t)(qt * 64 + w * 16 + l15) * (SNH * SDH) + lg * 8;
#pragma unroll
    for (int kk = 0; kk < 4; ++kk) {
      qfA[kk] = *(const s16x8*)(qp + hA * SDH + kk * 32);
      qfB[kk] = *(const s16x8*)(qp + hB * SDH + kk * 32);
    }
  }
  float mrowA[4], lrowA[4], mrowB[4], lrowB[4];
  f32x4 oaccA[8], oaccB[8];
#pragma unroll
  for (int j = 0; j < 4; ++j) {
    mrowA[j] = -1e30f; lrowA[j] = 0.f;
    mrowB[j] = -1e30f; lrowB[j] = 0.f;
  }
#pragma unroll
  for (int nd = 0; nd < 8; ++nd) {
    oaccA[nd] = (f32x4){0.f, 0.f, 0.f, 0.f};
    oaccB[nd] = (f32x4){0.f, 0.f, 0.f, 0.f};
  }

  STAGE_V(0, 0);
  STAGE_K(0);
  LOAD_BIAS(0, bbA, hA);
  LOAD_BIAS(0, bbB, hB);

  // one head's QK -> bias/mask -> online softmax; s becomes P values
#define QK_SM(QF, BB, MROW, LROW, OACC) do {                                  \
    __builtin_amdgcn_s_setprio(1);                                            \
    _Pragma("unroll") for (int ni = 0; ni < 4; ++ni) {                        \
      s[ni] = (f32x4){0.f, 0.f, 0.f, 0.f};                                    \
      const int r = ni * 16 + l15;                                            \
      _Pragma("unroll") for (int kk = 0; kk < 4; ++kk) {                      \
        const int cc = kk * 4 + lg;                                           \
        s16x8 kf = *(const s16x8*)(Ks + (r * 16 + (cc ^ (r & 7))) * 8);       \
        s[ni] = __builtin_amdgcn_mfma_f32_16x16x32_bf16(QF[kk], kf, s[ni], 0, 0, 0); \
      }                                                                       \
    }                                                                         \
    __builtin_amdgcn_s_setprio(0);                                            \
    _Pragma("unroll") for (int ni = 0; ni < 4; ++ni) {                        \
      _Pragma("unroll") for (int j = 0; j < 4; ++j) {                         \
        float sv = s[ni][j] + BB[ni][j];                                      \
        if (it == qt && kv0 + ni * 16 + l15 > qrow0 + j) sv = -1e30f;         \
        s[ni][j] = sv;                                                        \
      }                                                                       \
    }                                                                         \
    float pmax[4];                                                            \
    _Pragma("unroll") for (int j = 0; j < 4; ++j) {                           \
      float mx = fmaxf(fmaxf(s[0][j], s[1][j]), fmaxf(s[2][j], s[3][j]));     \
      pmax[j] = rowmax16(mx);                                                 \
    }                                                                         \
    bool need = (pmax[0] > MROW[0] + 8.f) | (pmax[1] > MROW[1] + 8.f) |       \
                (pmax[2] > MROW[2] + 8.f) | (pmax[3] > MROW[3] + 8.f);        \
    if (__any(need)) {                                                        \
      _Pragma("unroll") for (int j = 0; j < 4; ++j) {                         \
        const float mn = fmaxf(MROW[j], pmax[j]);                             \
        const float fsj = __expf(MROW[j] - mn);                               \
        MROW[j] = mn;                                                         \
        LROW[j] *= fsj;                                                       \
        _Pragma("unroll") for (int nd = 0; nd < 8; ++nd) OACC[nd][j] *= fsj;  \
      }                                                                       \
    }                                                                         \
    float ps[4] = {0.f, 0.f, 0.f, 0.f};                                       \
    _Pragma("unroll") for (int ni = 0; ni < 4; ++ni)                          \
      _Pragma("unroll") for (int j = 0; j < 4; ++j) {                         \
        const float pv = __expf(s[ni][j] - MROW[j]);                          \
        s[ni][j] = pv;                                                        \
        ps[j] += pv;                                                          \
      }                                                                       \
    _Pragma("unroll") for (int j = 0; j < 4; ++j) LROW[j] += rowsum16(ps[j]); \
  } while (0)

  // P (in s) -> wave-private LDS -> PV accumulate
#define PV(S, OACC, P) do {                                                   \
    _Pragma("unroll") for (int ni = 0; ni < 4; ++ni)                          \
      _Pragma("unroll") for (int j = 0; j < 4; ++j)                           \
        Ps[w][lg * 4 + j][ni * 16 + l15] = f2bf(S[ni][j]);                    \
    __builtin_amdgcn_s_setprio(1);                                            \
    _Pragma("unroll") for (int kk2 = 0; kk2 < 2; ++kk2) {                     \
      s16x8 pa = *(const s16x8*)&Ps[w][l15][kk2 * 32 + lg * 8];               \
      _Pragma("unroll") for (int nd = 0; nd < 8; ++nd) {                      \
        const int r = nd * 16 + l15;                                          \
        const int cc = kk2 * 4 + lg;                                          \
        s16x8 vf = *(const s16x8*)(Vs[P] + (r * 8 + (cc ^ (r & 7))) * 8);     \
        OACC[nd] = __builtin_amdgcn_mfma_f32_16x16x32_bf16(pa, vf, OACC[nd], 0, 0, 0); \
      }                                                                       \
    }                                                                         \
    __builtin_amdgcn_s_setprio(0);                                            \
  } while (0)

  for (int it = 0; it < nt; ++it) {
    const int p = it & 1;
    const int kv0 = it * 64;
    // drain V(it),K(it): the 8 oldest of {V4,K4,bias32}
    asm volatile("s_waitcnt vmcnt(32)" ::: "memory");
    __builtin_amdgcn_s_barrier();                      // B1: K/V published
    if (it + 1 < nt) STAGE_V(it + 1, p ^ 1);
    f32x4 s[4];
    f32x4 sB[4];
    // head A: QK + softmax (into s)
    QK_SM(qfA, bbA, mrowA, lrowA, oaccA);
#pragma unroll
    for (int ni = 0; ni < 4; ++ni) { sB[ni] = s[ni]; }  // hold P_A
    // head B: QK + softmax (into s)
    QK_SM(qfB, bbB, mrowB, lrowB, oaccB);
    __builtin_amdgcn_s_barrier();                      // B2: Ks reads done
    if (it + 1 < nt) {
      STAGE_K(it + 1);
      LOAD_BIAS(it + 1, bbA, hA);
      LOAD_BIAS(it + 1, bbB, hB);
    }
    // PV for head A (P_A held in sB), then head B (P_B in s)
    PV(sB, oaccA, p);
    PV(s, oaccB, p);
  }
#undef QK_SM
#undef PV
#undef STAGE_K
#undef STAGE_V
#undef LOAD_BIAS
  // ---- normalize + write both heads ----
#pragma unroll
  for (int j = 0; j < 4; ++j) {
    const float invA = 1.f / lrowA[j];
    const float invB = 1.f / lrowB[j];
    short* opA = o + (size_t)(qrow0 + j) * (SNH * SDH) + hA * SDH + l15;
    short* opB = o + (size_t)(qrow0 + j) * (SNH * SDH) + hB * SDH + l15;
#pragma unroll
    for (int nd = 0; nd < 8; ++nd) {
      opA[nd * 16] = f2bf(oaccA[nd][j] * invA);
      opB[nd * 16] = f2bf(oaccB[nd][j] * invB);
    }
  }
}

extern "C" void kernel_launch(void* const* d_in, const int* in_sizes, int n_in,
                              void* d_out, int out_size, void* d_ws, size_t ws_size,
                              hipStream_t stream) {
  (void)in_sizes; (void)n_in; (void)out_size; (void)ws_size;
  const float* hq   = (const float*)d_in[0];
  const float* hkv  = (const float*)d_in[1];
  const float* bias = (const float*)d_in[3];
  const float* Wq   = (const float*)d_in[4];
  const float* Wk   = (const float*)d_in[5];
  const float* Wv   = (const float*)d_in[6];
  const float* Wo   = (const float*)d_in[7];

  short* ws = (short*)d_ws;
  const size_t MEG = 1048576;
  short* hqb  = ws;
  short* hkvb = ws + 8 * MEG;
  short* WT   = ws + 16 * MEG;
  short* WkvT = ws + 32 * MEG;
  short* qb   = ws + 40 * MEG;
  short* kb   = ws + 48 * MEG;
  short* vbT  = ws + 50 * MEG;
  short* ob   = hqb;

  const float inv4 = 0.29730177875068026f;  // 128^-0.25

  convert_bf16<<<8192, 256, 0, stream>>>(hq,  hqb,  2097152);
  convert_bf16<<<8192, 256, 0, stream>>>(hkv, hkvb, 2097152);

  transpose_convert<<<dim3(64, 64), 256, 0, stream>>>(Wq, WT, 4096, 4096);
  gemm_big<0><<<256, 512, 0, stream>>>(hqb, WT, qb, inv4);

  transpose_convert<<<dim3(16, 64), 256, 0, stream>>>(Wk, WkvT, 4096, 1024);
  transpose_convert<<<dim3(16, 64), 256, 0, stream>>>(Wv, WkvT + (size_t)1024 * 4096, 4096, 1024);
  gemm_kv<<<256, 256, 0, stream>>>(hkvb, WkvT, kb, vbT, inv4);

  attn_kernel<<<512, 256, 0, stream>>>(qb, kb, vbT, bias, ob);

  transpose_convert<<<dim3(64, 64), 256, 0, stream>>>(Wo, WT, 4096, 4096);
  gemm_big<1><<<256, 512, 0, stream>>>(ob, WT, (float*)d_out, 1.0f);
}

// Round 17
// 415.058 us; speedup vs baseline: 1.0989x; 1.0989x over previous
//
#include <hip/hip_runtime.h>
#include <hip/hip_bf16.h>
#include <cstdint>
#include <cstddef>

typedef __attribute__((ext_vector_type(4))) float f32x4;
typedef __attribute__((ext_vector_type(4))) short s16x4;
typedef __attribute__((ext_vector_type(8))) short s16x8;

#define SLQ 2048
#define SLK 2048
#define SNH 32
#define SDH 128

__device__ __forceinline__ short f2bf(float x) {
  unsigned u = __builtin_bit_cast(unsigned, x);
  u += 0x7FFF + ((u >> 16) & 1);   // round-to-nearest-even
  return (short)(u >> 16);
}

__device__ __forceinline__ void gload_lds16(const void* g, const void* l) {
  __builtin_amdgcn_global_load_lds((const __attribute__((address_space(1))) void*)g,
                                   (__attribute__((address_space(3))) void*)l,
                                   16, 0, 0);
}

// DPP 16-lane-row reductions (VALU pipe): row_ror:8/4/2/1
template<int CTRL>
__device__ __forceinline__ float dpp_f32(float x) {
  return __builtin_bit_cast(float, __builtin_amdgcn_update_dpp(
      0, __builtin_bit_cast(int, x), CTRL, 0xF, 0xF, true));
}
__device__ __forceinline__ float rowmax16(float x) {
  x = fmaxf(x, dpp_f32<0x128>(x));
  x = fmaxf(x, dpp_f32<0x124>(x));
  x = fmaxf(x, dpp_f32<0x122>(x));
  x = fmaxf(x, dpp_f32<0x121>(x));
  return x;
}
__device__ __forceinline__ float rowsum16(float x) {
  x += dpp_f32<0x128>(x);
  x += dpp_f32<0x124>(x);
  x += dpp_f32<0x122>(x);
  x += dpp_f32<0x121>(x);
  return x;
}

// f32 -> bf16 elementwise
__global__ void convert_bf16(const float* __restrict__ in, short* __restrict__ out, int n4) {
  int i = blockIdx.x * 256 + threadIdx.x;
  if (i < n4) {
    f32x4 a = ((const f32x4*)in)[i];
    s16x4 b;
    b[0] = f2bf(a[0]); b[1] = f2bf(a[1]); b[2] = f2bf(a[2]); b[3] = f2bf(a[3]);
    ((s16x4*)out)[i] = b;
  }
}

// W [K][N] f32 -> Wt [N][K] bf16. 64x64 tiles.
__global__ void transpose_convert(const float* __restrict__ W, short* __restrict__ Wt,
                                  int K, int N) {
  __shared__ short T[64][68];
  const int tid = threadIdx.x;
  const int k0 = blockIdx.y * 64, n0 = blockIdx.x * 64;
  const int r = tid >> 4;
  const int c4 = (tid & 15) * 4;
#pragma unroll
  for (int i = 0; i < 4; ++i) {
    f32x4 a = *(const f32x4*)(W + (size_t)(k0 + r + i * 16) * N + n0 + c4);
#pragma unroll
    for (int j = 0; j < 4; ++j) T[c4 + j][r + i * 16] = f2bf(a[j]);
  }
  __syncthreads();
  const int rn = tid >> 3;
  const int c8 = (tid & 7) * 8;
#pragma unroll
  for (int i = 0; i < 2; ++i) {
    s16x4 v0 = *(const s16x4*)&T[rn + i * 32][c8];
    s16x4 v1 = *(const s16x4*)&T[rn + i * 32][c8 + 4];
    short* dst = Wt + (size_t)(n0 + rn + i * 32) * K + k0 + c8;
    *(s16x4*)dst = v0;
    *(s16x4*)(dst + 4) = v1;
  }
}

// ---------------------------------------------------------------------------
// gemm_big: C[2048][4096] = A[2048][4096] @ Bt[4096][4096]^T * scale
// BM=128, BN=256, BK=64, 8 waves (2x4), 3-deep LDS pipeline, counted vmcnt.
// XCD column-affinity (r11, -6.5us): XCD x owns n-columns {2x,2x+1}.
// ---------------------------------------------------------------------------
template<int CM>
__global__ __launch_bounds__(512, 1)
void gemm_big(const short* __restrict__ A, const short* __restrict__ Bt,
              void* __restrict__ Cv, float scale) {
  __shared__ short As[3][128 * 64];
  __shared__ short Bs[3][256 * 64];
  const int N = 4096, K = 4096;
  const int tid = threadIdx.x, lane = tid & 63, w = tid >> 6;
  const int l15 = lane & 15, lg = lane >> 4;
  const int wr = w >> 2, wc = w & 3;
  const int b = blockIdx.x;
  const int cp = b & 7, wi = b >> 3;
  const int m0 = (wi >> 1) * 128;
  const int n0 = (cp * 2 + (wi & 1)) * 256;

  f32x4 acc[4][4];
#pragma unroll
  for (int a = 0; a < 4; ++a)
#pragma unroll
    for (int c = 0; c < 4; ++c)
      acc[a][c] = (f32x4){0.f, 0.f, 0.f, 0.f};

#define GSTAGE(T, BUF) do {                                                    \
    _Pragma("unroll") for (int i_ = 0; i_ < 2; ++i_) {                         \
      const int ci = i_ * 512 + tid, r_ = ci >> 3, c_ = ci & 7;                \
      gload_lds16(A + (size_t)(m0 + r_) * K + (T) * 64 + ((c_ ^ (r_ & 7)) * 8),\
                  (const short*)As[BUF] + ci * 8); }                           \
    _Pragma("unroll") for (int i_ = 0; i_ < 4; ++i_) {                         \
      const int ci = i_ * 512 + tid, r_ = ci >> 3, c_ = ci & 7;                \
      gload_lds16(Bt + (size_t)(n0 + r_) * K + (T) * 64 + ((c_ ^ (r_ & 7)) * 8),\
                  (const short*)Bs[BUF] + ci * 8); }                           \
  } while (0)

  const int NT = K >> 6;
  GSTAGE(0, 0); GSTAGE(1, 1); GSTAGE(2, 2);
  int buf = 0;
  for (int t = 0; t < NT; ++t) {
    if (t + 2 < NT)      asm volatile("s_waitcnt vmcnt(12)" ::: "memory");
    else if (t + 1 < NT) asm volatile("s_waitcnt vmcnt(6)" ::: "memory");
    else                 asm volatile("s_waitcnt vmcnt(0)" ::: "memory");
    __builtin_amdgcn_s_barrier();
    const short* Ab = As[buf];
    const short* Bb = Bs[buf];
    s16x8 af[2][4], bfv[2][4];
#pragma unroll
    for (int kk = 0; kk < 2; ++kk) {
#pragma unroll
      for (int mi = 0; mi < 4; ++mi) {
        const int r = wr * 64 + mi * 16 + l15;
        const int c = (kk * 4 + lg) ^ (r & 7);
        af[kk][mi] = *(const s16x8*)(Ab + (r * 8 + c) * 8);
      }
#pragma unroll
      for (int ni = 0; ni < 4; ++ni) {
        const int r = wc * 64 + ni * 16 + l15;
        const int c = (kk * 4 + lg) ^ (r & 7);
        bfv[kk][ni] = *(const s16x8*)(Bb + (r * 8 + c) * 8);
      }
    }
    __builtin_amdgcn_s_setprio(1);
#pragma unroll
    for (int kk = 0; kk < 2; ++kk)
#pragma unroll
      for (int mi = 0; mi < 4; ++mi)
#pragma unroll
        for (int ni = 0; ni < 4; ++ni)
          acc[mi][ni] = __builtin_amdgcn_mfma_f32_16x16x32_bf16(af[kk][mi], bfv[kk][ni], acc[mi][ni], 0, 0, 0);
    __builtin_amdgcn_s_setprio(0);
    __builtin_amdgcn_s_barrier();
    if (t + 3 < NT) GSTAGE(t + 3, buf);
    buf = (buf == 2) ? 0 : buf + 1;
  }
#undef GSTAGE
#pragma unroll
  for (int mi = 0; mi < 4; ++mi) {
#pragma unroll
    for (int ni = 0; ni < 4; ++ni) {
#pragma unroll
      for (int j = 0; j < 4; ++j) {
        const int rg = m0 + wr * 64 + mi * 16 + lg * 4 + j;
        const int cg = n0 + wc * 64 + ni * 16 + l15;
        const float vv = acc[mi][ni][j] * scale;
        if (CM == 0) ((short*)Cv)[(size_t)rg * N + cg] = f2bf(vv);
        else         ((float*)Cv)[(size_t)rg * N + cg] = vv;
      }
    }
  }
}

// ---------------------------------------------------------------------------
// gemm_kv: fused K,V projection. n < 1024 -> kout*inv4 ; else vT transposed.
// ---------------------------------------------------------------------------
__global__ __launch_bounds__(256, 2)
void gemm_kv(const short* __restrict__ A, const short* __restrict__ Bt,
             short* __restrict__ kout, short* __restrict__ vTout, float inv4) {
  __shared__ short As[128][32];
  __shared__ short Bs[128][32];
  const int N = 2048, K = 4096;
  const int tid = threadIdx.x, lane = tid & 63, wid = tid >> 6;
  const int l15 = lane & 15, lg = lane >> 4;
  const int nbx = N >> 7;
  const int nwg = gridDim.x, b = blockIdx.x;
  const int wg = (b & 7) * (nwg >> 3) + (b >> 3);
  const int m0 = (wg / nbx) * 128, n0 = (wg % nbx) * 128;
  const int wm = (wid >> 1) * 64, wn = (wid & 1) * 64;

  f32x4 acc[4][4];
#pragma unroll
  for (int a = 0; a < 4; ++a)
#pragma unroll
    for (int c = 0; c < 4; ++c)
      acc[a][c] = (f32x4){0.f, 0.f, 0.f, 0.f};

  for (int k0 = 0; k0 < K; k0 += 32) {
#pragma unroll
    for (int i = 0; i < 2; ++i) {
      const int c = i * 256 + wid * 64 + lane;
      const int rr = c >> 2, hh = (c & 3) * 8;
      gload_lds16(A  + (size_t)(m0 + rr) * K + k0 + hh,
                  (const short*)As + (size_t)(i * 256 + wid * 64) * 8);
      gload_lds16(Bt + (size_t)(n0 + rr) * K + k0 + hh,
                  (const short*)Bs + (size_t)(i * 256 + wid * 64) * 8);
    }
    __syncthreads();
    s16x8 af[4], bf[4];
#pragma unroll
    for (int mi = 0; mi < 4; ++mi)
      af[mi] = *(const s16x8*)&As[wm + mi * 16 + l15][lg * 8];
#pragma unroll
    for (int ni = 0; ni < 4; ++ni)
      bf[ni] = *(const s16x8*)&Bs[wn + ni * 16 + l15][lg * 8];
#pragma unroll
    for (int mi = 0; mi < 4; ++mi)
#pragma unroll
      for (int ni = 0; ni < 4; ++ni)
        acc[mi][ni] = __builtin_amdgcn_mfma_f32_16x16x32_bf16(af[mi], bf[ni], acc[mi][ni], 0, 0, 0);
    __syncthreads();
  }
  if (n0 < 1024) {
#pragma unroll
    for (int mi = 0; mi < 4; ++mi)
#pragma unroll
      for (int ni = 0; ni < 4; ++ni)
#pragma unroll
        for (int j = 0; j < 4; ++j) {
          const int rg = m0 + wm + mi * 16 + lg * 4 + j;
          const int cg = n0 + wn + ni * 16 + l15;
          kout[(size_t)rg * 1024 + cg] = f2bf(acc[mi][ni][j] * inv4);
        }
  } else {
#pragma unroll
    for (int mi = 0; mi < 4; ++mi)
#pragma unroll
      for (int ni = 0; ni < 4; ++ni) {
        s16x4 wv;
#pragma unroll
        for (int j = 0; j < 4; ++j) wv[j] = f2bf(acc[mi][ni][j]);
        const int rg0 = m0 + wm + mi * 16 + lg * 4;
        const int cg = n0 + wn + ni * 16 + l15 - 1024;
        *(s16x4*)(vTout + (size_t)cg * 2048 + rg0) = wv;
      }
  }
}

// ---------------------------------------------------------------------------
// Flash attention v6' (converged best): v4 structure + bias staged to LDS via
// global_load_lds (un-sinkable, counted in vmcnt, full-tile flight),
// WAVE-SELF-LOADED rows (per-wave vmcnt drain sufficient, no cross-wave race).
// Chunk-XOR swizzle on Bb. LDS: K 16K + V dbuf 32K + Bb 16K + Ps 9K = 73 KB.
// vmcnt ledger: top vmcnt(4) drains V(it),K(it), leaves B(it);
// mid vmcnt(4) drains B(it), leaves V(it+1); tail vmcnt(0).
// ---------------------------------------------------------------------------
__global__ __launch_bounds__(256, 2)
void attn_kernel(const short* __restrict__ q, const short* __restrict__ k,
                 const short* __restrict__ vT, const float* __restrict__ bias,
                 short* __restrict__ o) {
  __shared__ __align__(16) short Ks[64 * 128];
  __shared__ __align__(16) short Vs[2][128 * 64];
  __shared__ __align__(16) float Bb[64 * 64];
  __shared__ __align__(16) short Ps[4][16][72];
  const int tid = threadIdx.x, lane = tid & 63, w = tid >> 6;
  const int l15 = lane & 15, lg = lane >> 4;
  const int b = blockIdx.x;
  const int h = b & 31;
  const int qt = 31 - (b >> 5);      // long blocks first
  const int kvh = h >> 2;
  const int nt = qt + 1;

#define STAGE_K(IT) do { const int kv0_ = (IT) * 64;                          \
    _Pragma("unroll") for (int i_ = 0; i_ < 4; ++i_) {                        \
      const int ci = i_ * 256 + tid, r_ = ci >> 4, c_ = ci & 15;              \
      gload_lds16(k + (size_t)(kv0_ + r_) * 1024 + kvh * 128 + ((c_ ^ (r_ & 7)) * 8), \
                  (const short*)Ks + ci * 8); } } while (0)

#define STAGE_V(IT, P) do { const int kv0_ = (IT) * 64;                       \
    _Pragma("unroll") for (int i_ = 0; i_ < 4; ++i_) {                        \
      const int ci = i_ * 256 + tid, r_ = ci >> 3, c_ = ci & 7;               \
      gload_lds16(vT + (size_t)(kvh * 128 + r_) * 2048 + kv0_ + ((c_ ^ (r_ & 7)) * 8), \
                  (const short*)Vs[P] + ci * 8); } } while (0)

// bias 64x64 f32 tile, wave-self rows: wave w stages rows [w*16, w*16+16),
// 16B chunks XOR-swizzled by row&7 (source pre-swizzled, LDS dest linear).
#define STAGE_B(IT) do { const int kv0_ = (IT) * 64;                          \
    _Pragma("unroll") for (int i_ = 0; i_ < 4; ++i_) {                        \
      const int li = i_ * 64 + lane, r_ = w * 16 + (li >> 4), c_ = li & 15;   \
      gload_lds16(bias + ((size_t)h * SLQ + qt * 64 + r_) * SLK + kv0_ + ((c_ ^ (r_ & 7)) * 4), \
                  (const float*)Bb + ((size_t)w * 256 + li) * 4); } } while (0)

  const int qrow0 = qt * 64 + w * 16 + lg * 4;

  s16x8 qf[4];
  {
    const short* qp = q + (size_t)(qt * 64 + w * 16 + l15) * (SNH * SDH) + h * SDH + lg * 8;
#pragma unroll
    for (int kk = 0; kk < 4; ++kk) qf[kk] = *(const s16x8*)(qp + kk * 32);
  }
  float mrow[4], lrow[4];
  f32x4 oacc[8];
#pragma unroll
  for (int j = 0; j < 4; ++j) { mrow[j] = -1e30f; lrow[j] = 0.f; }
#pragma unroll
  for (int nd = 0; nd < 8; ++nd) oacc[nd] = (f32x4){0.f, 0.f, 0.f, 0.f};

  STAGE_V(0, 0);
  STAGE_K(0);
  STAGE_B(0);

  for (int it = 0; it < nt; ++it) {
    const int p = it & 1;
    const int kv0 = it * 64;
    asm volatile("s_waitcnt vmcnt(4)" ::: "memory");   // V(it),K(it) drained; B(it) flies
    __builtin_amdgcn_s_barrier();                      // B1: K/V published
    if (it + 1 < nt) STAGE_V(it + 1, p ^ 1);
    // ---- S = Q K^T from LDS ----
    f32x4 s[4];
    __builtin_amdgcn_s_setprio(1);
#pragma unroll
    for (int ni = 0; ni < 4; ++ni) {
      s[ni] = (f32x4){0.f, 0.f, 0.f, 0.f};
      const int r = ni * 16 + l15;
#pragma unroll
      for (int kk = 0; kk < 4; ++kk) {
        const int cc = kk * 4 + lg;
        s16x8 kf = *(const s16x8*)(Ks + (r * 16 + (cc ^ (r & 7))) * 8);
        s[ni] = __builtin_amdgcn_mfma_f32_16x16x32_bf16(qf[kk], kf, s[ni], 0, 0, 0);
      }
    }
    __builtin_amdgcn_s_setprio(0);
    // ---- drain OWN bias rows (wave-self-loaded -> sufficient) ----
    if (it + 1 < nt) asm volatile("s_waitcnt vmcnt(4)" ::: "memory");
    else             asm volatile("s_waitcnt vmcnt(0)" ::: "memory");
    // ---- bias (from LDS, swizzled) + causal mask ----
#pragma unroll
    for (int ni = 0; ni < 4; ++ni) {
#pragma unroll
      for (int j = 0; j < 4; ++j) {
        const int rr = w * 16 + lg * 4 + j;
        const int ch = (ni * 4 + (l15 >> 2)) ^ (rr & 7);
        float sv = s[ni][j] + Bb[rr * 64 + ch * 4 + (l15 & 3)];
        if (it == qt && kv0 + ni * 16 + l15 > qrow0 + j) sv = -1e30f;
        s[ni][j] = sv;
      }
    }
    // ---- online softmax: DPP row reductions, defer-max (THR=8) ----
    float pmax[4];
#pragma unroll
    for (int j = 0; j < 4; ++j) {
      float mx = fmaxf(fmaxf(s[0][j], s[1][j]), fmaxf(s[2][j], s[3][j]));
      pmax[j] = rowmax16(mx);
    }
    bool need = (pmax[0] > mrow[0] + 8.f) | (pmax[1] > mrow[1] + 8.f) |
                (pmax[2] > mrow[2] + 8.f) | (pmax[3] > mrow[3] + 8.f);
    if (__any(need)) {
#pragma unroll
      for (int j = 0; j < 4; ++j) {
        const float mn = fmaxf(mrow[j], pmax[j]);
        const float fsj = __expf(mrow[j] - mn);
        mrow[j] = mn;
        lrow[j] *= fsj;
#pragma unroll
        for (int nd = 0; nd < 8; ++nd) oacc[nd][j] *= fsj;
      }
    }
    float ps[4] = {0.f, 0.f, 0.f, 0.f};
#pragma unroll
    for (int ni = 0; ni < 4; ++ni)
#pragma unroll
      for (int j = 0; j < 4; ++j) {
        const float pv = __expf(s[ni][j] - mrow[j]);
        s[ni][j] = pv;
        ps[j] += pv;
      }
#pragma unroll
    for (int j = 0; j < 4; ++j) lrow[j] += rowsum16(ps[j]);
    __builtin_amdgcn_s_barrier();                      // B2: Ks + Bb reads done
    if (it + 1 < nt) { STAGE_K(it + 1); STAGE_B(it + 1); }
    // ---- P -> wave-private LDS ----
#pragma unroll
    for (int ni = 0; ni < 4; ++ni)
#pragma unroll
      for (int j = 0; j < 4; ++j)
        Ps[w][lg * 4 + j][ni * 16 + l15] = f2bf(s[ni][j]);
    // ---- O += P V from LDS ----
    __builtin_amdgcn_s_setprio(1);
#pragma unroll
    for (int kk2 = 0; kk2 < 2; ++kk2) {
      s16x8 pa = *(const s16x8*)&Ps[w][l15][kk2 * 32 + lg * 8];
#pragma unroll
      for (int nd = 0; nd < 8; ++nd) {
        const int r = nd * 16 + l15;
        const int cc = kk2 * 4 + lg;
        s16x8 vf = *(const s16x8*)(Vs[p] + (r * 8 + (cc ^ (r & 7))) * 8);
        oacc[nd] = __builtin_amdgcn_mfma_f32_16x16x32_bf16(pa, vf, oacc[nd], 0, 0, 0);
      }
    }
    __builtin_amdgcn_s_setprio(0);
  }
#undef STAGE_K
#undef STAGE_V
#undef STAGE_B
#pragma unroll
  for (int j = 0; j < 4; ++j) {
    const float inv = 1.f / lrow[j];
    short* op = o + (size_t)(qrow0 + j) * (SNH * SDH) + h * SDH + l15;
#pragma unroll
    for (int nd = 0; nd < 8; ++nd)
      op[nd * 16] = f2bf(oacc[nd][j] * inv);
  }
}

extern "C" void kernel_launch(void* const* d_in, const int* in_sizes, int n_in,
                              void* d_out, int out_size, void* d_ws, size_t ws_size,
                              hipStream_t stream) {
  (void)in_sizes; (void)n_in; (void)out_size; (void)ws_size;
  const float* hq   = (const float*)d_in[0];
  const float* hkv  = (const float*)d_in[1];
  const float* bias = (const float*)d_in[3];
  const float* Wq   = (const float*)d_in[4];
  const float* Wk   = (const float*)d_in[5];
  const float* Wv   = (const float*)d_in[6];
  const float* Wo   = (const float*)d_in[7];

  short* ws = (short*)d_ws;
  const size_t MEG = 1048576;
  short* hqb  = ws;
  short* hkvb = ws + 8 * MEG;
  short* WT   = ws + 16 * MEG;
  short* WkvT = ws + 32 * MEG;
  short* qb   = ws + 40 * MEG;
  short* kb   = ws + 48 * MEG;
  short* vbT  = ws + 50 * MEG;
  short* ob   = hqb;

  const float inv4 = 0.29730177875068026f;  // 128^-0.25

  convert_bf16<<<8192, 256, 0, stream>>>(hq,  hqb,  2097152);
  convert_bf16<<<8192, 256, 0, stream>>>(hkv, hkvb, 2097152);

  transpose_convert<<<dim3(64, 64), 256, 0, stream>>>(Wq, WT, 4096, 4096);
  gemm_big<0><<<256, 512, 0, stream>>>(hqb, WT, qb, inv4);

  transpose_convert<<<dim3(16, 64), 256, 0, stream>>>(Wk, WkvT, 4096, 1024);
  transpose_convert<<<dim3(16, 64), 256, 0, stream>>>(Wv, WkvT + (size_t)1024 * 4096, 4096, 1024);
  gemm_kv<<<256, 256, 0, stream>>>(hkvb, WkvT, kb, vbT, inv4);

  attn_kernel<<<1024, 256, 0, stream>>>(qb, kb, vbT, bias, ob);

  transpose_convert<<<dim3(64, 64), 256, 0, stream>>>(Wo, WT, 4096, 4096);
  gemm_big<1><<<256, 512, 0, stream>>>(ob, WT, (float*)d_out, 1.0f);
}